// Round 1
// baseline (1189.317 us; speedup 1.0000x reference)
//
#include <hip/hip_runtime.h>
#include <hip/hip_bf16.h>

typedef __attribute__((ext_vector_type(8))) short bf16x8;
typedef __attribute__((ext_vector_type(4))) float f32x4;
typedef unsigned short ushort_t;

__device__ inline ushort_t f2bf(float f){
    union { float f; unsigned int u; } v; v.f = f;
    unsigned int r = v.u + 0x7fffu + ((v.u >> 16) & 1u);   // RNE
    return (ushort_t)(r >> 16);
}

// ---------------- weight transforms ----------------
// prim_w [256 oc][256 ic][81 p] f32  ->  w2t [oc][p][ic] bf16
__global__ __launch_bounds__(256) void k_w2t(const float* __restrict__ pw, ushort_t* __restrict__ w2t)
{
    __shared__ float tile[5184];             // [64 ic][81 p]
    const int oc  = blockIdx.x >> 2;
    const int ic0 = (blockIdx.x & 3) * 64;
    const float* src = pw + (oc*256 + ic0)*81;
    for (int j = threadIdx.x; j < 5184; j += 256) tile[j] = src[j];
    __syncthreads();
    for (int j = threadIdx.x; j < 5184; j += 256){
        int p = j >> 6, ic = j & 63;
        w2t[(oc*81 + p)*256 + ic0 + ic] = f2bf(tile[ic*81 + p]);
    }
}

// conv_w [256 oc][243 k] f32 -> cwt [243 k][256 oc] f32
__global__ void k_cwt(const float* __restrict__ cw, float* __restrict__ cwt){
    int k = blockIdx.x;           // 0..242
    int oc = threadIdx.x;         // 0..255
    cwt[k*256 + oc] = cw[oc*243 + k];
}

// ---------------- conv1 (fp32 direct) -> h_t[b][24][24][256] bf16 ----------------
__global__ __launch_bounds__(256) void k_conv1(const float* __restrict__ x,
    const float* __restrict__ cwt, const float* __restrict__ conv_b,
    ushort_t* __restrict__ ht)
{
    const int oy = blockIdx.x;    // 0..23
    const int b  = blockIdx.y;    // 0..127
    const int oc = threadIdx.x;   // 0..255
    float acc[24];
    const float bias = conv_b[oc];
    #pragma unroll
    for (int i=0;i<24;i++) acc[i] = bias;
    for (int ic=0; ic<3; ic++){
        for (int ky=0; ky<9; ky++){
            const float* xr = x + ((b*3 + ic)*32 + (oy+ky))*32;
            float xv[32];
            #pragma unroll
            for (int j=0;j<32;j++) xv[j] = xr[j];        // wave-uniform loads
            const float* wrow = cwt + (ic*81 + ky*9)*256 + oc;
            #pragma unroll
            for (int kx=0; kx<9; kx++){
                float w = wrow[kx*256];
                #pragma unroll
                for (int ox=0; ox<24; ox++) acc[ox] += xv[ox+kx]*w;
            }
        }
    }
    ushort_t* dst = ht + ((b*24 + oy)*24)*256 + oc;
    #pragma unroll
    for (int ox=0; ox<24; ox++){
        float v = acc[ox];
        v = v > 0.f ? v : 0.01f*v;                        // leaky_relu
        dst[ox*256] = f2bf(v);
    }
}

// ---------------- conv2 as bf16 MFMA GEMM (im2col), K-split 4 ----------------
// A[m][k] = ht[b][2oy+ky][2ox+kx][ic], m=b*64+oy*8+ox, k=(ky*9+kx)*256+ic
// B[n][k] = w2t[oc][p][ic].  C -> p2p[ks][m][n] f32
__global__ __launch_bounds__(256) void k_conv2gemm(const ushort_t* __restrict__ ht,
    const ushort_t* __restrict__ w2t, float* __restrict__ p2p)
{
    __shared__ ushort_t At[128*64];
    __shared__ ushort_t Bt[64*64];
    const int tid = threadIdx.x;
    const int bid = blockIdx.x;
    const int mt = bid & 63, rest = bid >> 6;   // same-mt blocks share XCD (bid%8==mt%8)
    const int nt = rest & 3, ks = rest >> 2;
    const int m0 = mt*128, n0 = nt*64;
    const int lane = tid & 63, wave = tid >> 6;
    const int wm = (wave>>1)*64, wn = (wave&1)*32;
    const int l16 = lane & 15, lq = lane >> 4;

    f32x4 acc[4][2];
    #pragma unroll
    for (int i=0;i<4;i++)
        #pragma unroll
        for (int j=0;j<2;j++) acc[i][j] = 0;

    const ushort_t* abase[4];
    int aco[4];
    #pragma unroll
    for (int t=0;t<4;t++){
        int cid = tid + t*256;
        int row = cid>>3; aco[t] = cid&7;
        int m = m0 + row; int b = m>>6; int hw = m&63;
        int oy2 = hw>>3, ox2 = hw&7;
        abase[t] = ht + (((b*24 + 2*oy2)*24) + 2*ox2)*256;
    }
    int brow[2], bco[2];
    #pragma unroll
    for (int t=0;t<2;t++){
        int cid = tid + t*256;
        brow[t] = cid>>3; bco[t] = cid&7;
    }

    const int k_begin = ks*5184, k_end = k_begin + 5184;
    for (int k0 = k_begin; k0 < k_end; k0 += 64){
        const int p   = k0 >> 8;
        const int ky  = p/9, kx = p - ky*9;
        const int ic0 = k0 & 255;
        #pragma unroll
        for (int t=0;t<4;t++){
            bf16x8 v = *(const bf16x8*)(abase[t] + (ky*24 + kx)*256 + ic0 + aco[t]*8);
            *(bf16x8*)&At[(tid + t*256)*8] = v;
        }
        #pragma unroll
        for (int t=0;t<2;t++){
            bf16x8 v = *(const bf16x8*)(w2t + (n0+brow[t])*20736 + p*256 + ic0 + bco[t]*8);
            *(bf16x8*)&Bt[(tid + t*256)*8] = v;
        }
        __syncthreads();
        #pragma unroll
        for (int kk=0; kk<2; kk++){
            bf16x8 a[4], bf[2];
            const int kb = kk*32 + lq*8;
            #pragma unroll
            for (int f=0; f<4; f++) a[f]  = *(const bf16x8*)&At[(wm + f*16 + l16)*64 + kb];
            #pragma unroll
            for (int f=0; f<2; f++) bf[f] = *(const bf16x8*)&Bt[(wn + f*16 + l16)*64 + kb];
            #pragma unroll
            for (int i=0;i<4;i++)
                #pragma unroll
                for (int j=0;j<2;j++)
                    acc[i][j] = __builtin_amdgcn_mfma_f32_16x16x32_bf16(a[i], bf[j], acc[i][j], 0,0,0);
        }
        __syncthreads();
    }
    float* dst = p2p + (size_t)ks*2097152;
    #pragma unroll
    for (int i=0;i<4;i++)
        #pragma unroll
        for (int j=0;j<2;j++)
            #pragma unroll
            for (int r=0;r<4;r++){
                int m = m0 + wm + i*16 + lq*4 + r;          // C/D: row=(l>>4)*4+reg
                int n = n0 + wn + j*16 + l16;               //      col=l&15
                dst[m*256 + n] = acc[i][j][r];
            }
}

// ---------------- p (+bias) -> u (squashed), u[b][n=hw*32+cap][8] ----------------
__global__ __launch_bounds__(256) void k_squash_u(const float* __restrict__ p2p,
    const float* __restrict__ prim_b, float* __restrict__ u)
{
    const int idx = blockIdx.x*256 + threadIdx.x;  // 0..262143 = b*2048+n
    const int b = idx >> 11, n = idx & 2047;
    const int hw = n >> 5, cap = n & 31;
    const int base = (b*64 + hw)*256 + cap*8;
    float v[8];
    #pragma unroll
    for (int j=0;j<8;j++) v[j] = prim_b[cap*8+j];
    #pragma unroll
    for (int ksp=0; ksp<4; ksp++){
        const float* sp = p2p + (size_t)ksp*2097152 + base;
        #pragma unroll
        for (int j=0;j<8;j++) v[j] += sp[j];
    }
    float s = 0.f;
    #pragma unroll
    for (int j=0;j<8;j++) s += v[j]*v[j];
    const float sc = sqrtf(s)/(1.0f + s);
    float* dst = u + (size_t)idx*8;
    #pragma unroll
    for (int j=0;j<8;j++) dst[j] = v[j]*sc;
}

// ---------------- routing: per-8-node-chunk, dig_w slice in LDS ----------------
// mode 0: probs uniform 0.1 (iter 1, logits==0). mode 1: logits = delta (first update).
// mode 2: logits += delta.  Writes partials[chunk][b][c*16+d].
__global__ __launch_bounds__(192) void k_route(const float* __restrict__ u,
    const float* __restrict__ dw, float* __restrict__ logits,
    const float* __restrict__ outv, float* __restrict__ partials, const int mode)
{
    __shared__ float Wl[10*8*128];   // [c][nl][i*16+d]  40 KB
    __shared__ float ul[64];         // [nl][i]
    __shared__ float outl[160];      // [c][d]
    __shared__ float ll[80];         // [c][nl]
    __shared__ float pl[80];         // [c][nl]
    const int tid = threadIdx.x;
    const int chunk = blockIdx.x & 255;
    const int b0 = (blockIdx.x >> 8) * 32;
    const int n0 = chunk * 8;
    for (int j = tid; j < 10240; j += 192){
        int c = j >> 10, r = j & 1023;
        Wl[j] = dw[(size_t)c*262144 + n0*128 + r];
    }
    const int c_ = tid >> 4, dl = tid & 15;
    __syncthreads();
    for (int b = b0; b < b0+32; b++){
        if (tid < 64) ul[tid] = u[((size_t)b*2048 + n0)*8 + tid];
        if (mode && tid < 160) outl[tid] = outv[b*160 + tid];
        __syncthreads();
        if (mode && tid < 160 && (tid & 15) < 8){
            const int c = c_, nl = tid & 7;
            float delta = 0.f;
            #pragma unroll
            for (int i=0;i<8;i++){
                float tmp = 0.f;
                const float* wr = &Wl[(c*8 + nl)*128 + i*16];
                #pragma unroll
                for (int d=0; d<16; d++) tmp += wr[d]*outl[c*16+d];
                delta += ul[nl*8+i]*tmp;
            }
            const size_t gi = ((size_t)b*10 + c)*2048 + n0 + nl;
            const float ln = (mode==1 ? 0.f : logits[gi]) + delta;
            logits[gi] = ln;
            ll[c*8 + nl] = ln;
        }
        __syncthreads();
        if (mode && tid < 8){
            float mx = ll[tid];
            #pragma unroll
            for (int c=1;c<10;c++) mx = fmaxf(mx, ll[c*8+tid]);
            float e[10], s = 0.f;
            #pragma unroll
            for (int c=0;c<10;c++){ e[c] = __expf(ll[c*8+tid]-mx); s += e[c]; }
            const float inv = 1.f/s;
            #pragma unroll
            for (int c=0;c<10;c++) pl[c*8+tid] = e[c]*inv;
        }
        __syncthreads();
        if (tid < 160){
            float a = 0.f;
            #pragma unroll
            for (int nl=0; nl<8; nl++){
                float uh = 0.f;
                const float* wr = &Wl[(c_*8 + nl)*128 + dl];
                #pragma unroll
                for (int i=0;i<8;i++) uh += ul[nl*8+i]*wr[i*16];
                const float pr = mode ? pl[c_*8+nl] : 0.1f;
                a += pr*uh;
            }
            partials[((size_t)chunk*128 + b)*160 + tid] = a;
        }
        __syncthreads();
    }
}

// out[b][c][d] = squash_d( sum_chunks partials )
__global__ __launch_bounds__(192) void k_reduce_out(const float* __restrict__ partials,
                                                    float* __restrict__ outv)
{
    const int b = blockIdx.x;
    const int t = threadIdx.x;
    if (t >= 160) return;
    float s = 0.f;
    const float* p = partials + (size_t)b*160 + t;
    #pragma unroll 8
    for (int ch=0; ch<256; ch++) s += p[(size_t)ch*20480];
    float ss = s*s;
    ss += __shfl_xor(ss, 1, 16);
    ss += __shfl_xor(ss, 2, 16);
    ss += __shfl_xor(ss, 4, 16);
    ss += __shfl_xor(ss, 8, 16);
    outv[b*160 + t] = s * sqrtf(ss)/(1.f + ss);
}

extern "C" void kernel_launch(void* const* d_in, const int* in_sizes, int n_in,
                              void* d_out, int out_size, void* d_ws, size_t ws_size,
                              hipStream_t stream)
{
    const float* x      = (const float*)d_in[0];
    const float* conv_w = (const float*)d_in[1];
    const float* conv_b = (const float*)d_in[2];
    const float* prim_w = (const float*)d_in[3];
    const float* prim_b = (const float*)d_in[4];
    const float* dig_w  = (const float*)d_in[5];
    float* out = (float*)d_out;
    char* ws = (char*)d_ws;

    // layout (bytes). logits/partials/outw overlay dead h_t region. peak = 90.6 MB
    ushort_t* ht       = (ushort_t*)(ws + 0);           // 37,748,736
    float*    logits   = (float*)   (ws + 0);           // 10,485,760 (overlay)
    float*    partials = (float*)   (ws + 10485760);    // 20,971,520 (overlay)
    float*    outw     = (float*)   (ws + 31457280);    //     81,920 (overlay)
    ushort_t* w2t      = (ushort_t*)(ws + 37748736);    // 10,616,832
    float*    cwt      = (float*)   (ws + 48365568);    //    248,832
    float*    p2p      = (float*)   (ws + 48614400);    // 33,554,432
    float*    u        = (float*)   (ws + 82168832);    //  8,388,608  -> 90,557,440 total

    k_w2t<<<1024, 256, 0, stream>>>(prim_w, w2t);
    k_cwt<<<243, 256, 0, stream>>>(conv_w, cwt);
    k_conv1<<<dim3(24,128), 256, 0, stream>>>(x, cwt, conv_b, ht);
    k_conv2gemm<<<1024, 256, 0, stream>>>(ht, w2t, p2p);
    k_squash_u<<<1024, 256, 0, stream>>>(p2p, prim_b, u);

    // routing: out1(uniform) -> l1 -> out2 -> l2 -> out3 -> l3 -> out4(final)
    k_route<<<1024, 192, 0, stream>>>(u, dig_w, logits, outw, partials, 0);
    k_reduce_out<<<128, 192, 0, stream>>>(partials, outw);
    k_route<<<1024, 192, 0, stream>>>(u, dig_w, logits, outw, partials, 1);
    k_reduce_out<<<128, 192, 0, stream>>>(partials, outw);
    k_route<<<1024, 192, 0, stream>>>(u, dig_w, logits, outw, partials, 2);
    k_reduce_out<<<128, 192, 0, stream>>>(partials, outw);
    k_route<<<1024, 192, 0, stream>>>(u, dig_w, logits, outw, partials, 2);
    k_reduce_out<<<128, 192, 0, stream>>>(partials, out);
}

// Round 2
// 743.544 us; speedup vs baseline: 1.5995x; 1.5995x over previous
//
#include <hip/hip_runtime.h>
#include <hip/hip_bf16.h>

typedef __attribute__((ext_vector_type(8))) short bf16x8;
typedef __attribute__((ext_vector_type(4))) float f32x4;
typedef unsigned short ushort_t;

__device__ inline ushort_t f2bf(float f){
    union { float f; unsigned int u; } v; v.f = f;
    unsigned int r = v.u + 0x7fffu + ((v.u >> 16) & 1u);   // RNE
    return (ushort_t)(r >> 16);
}

// ---------------- weight transforms ----------------
// prim_w [256 oc][256 ic][81 p] f32  ->  w2t [oc][p][ic] bf16
__global__ __launch_bounds__(256) void k_w2t(const float* __restrict__ pw, ushort_t* __restrict__ w2t)
{
    __shared__ float tile[5184];             // [64 ic][81 p]
    const int oc  = blockIdx.x >> 2;
    const int ic0 = (blockIdx.x & 3) * 64;
    const float* src = pw + (oc*256 + ic0)*81;
    for (int j = threadIdx.x; j < 5184; j += 256) tile[j] = src[j];
    __syncthreads();
    for (int j = threadIdx.x; j < 5184; j += 256){
        int p = j >> 6, ic = j & 63;
        w2t[(oc*81 + p)*256 + ic0 + ic] = f2bf(tile[ic*81 + p]);
    }
}

// conv_w [256 oc][243 k] f32 -> cwt [243 k][256 oc] f32
__global__ void k_cwt(const float* __restrict__ cw, float* __restrict__ cwt){
    int k = blockIdx.x;           // 0..242
    int oc = threadIdx.x;         // 0..255
    cwt[k*256 + oc] = cw[oc*243 + k];
}

// ---------------- conv1 (fp32 direct) -> h_t[b][24][24][256] bf16 ----------------
__global__ __launch_bounds__(256) void k_conv1(const float* __restrict__ x,
    const float* __restrict__ cwt, const float* __restrict__ conv_b,
    ushort_t* __restrict__ ht)
{
    const int oy = blockIdx.x;    // 0..23
    const int b  = blockIdx.y;    // 0..127
    const int oc = threadIdx.x;   // 0..255
    float acc[24];
    const float bias = conv_b[oc];
    #pragma unroll
    for (int i=0;i<24;i++) acc[i] = bias;
    for (int ic=0; ic<3; ic++){
        for (int ky=0; ky<9; ky++){
            const float* xr = x + ((b*3 + ic)*32 + (oy+ky))*32;
            float xv[32];
            #pragma unroll
            for (int j=0;j<32;j++) xv[j] = xr[j];        // wave-uniform loads
            const float* wrow = cwt + (ic*81 + ky*9)*256 + oc;
            #pragma unroll
            for (int kx=0; kx<9; kx++){
                float w = wrow[kx*256];
                #pragma unroll
                for (int ox=0; ox<24; ox++) acc[ox] += xv[ox+kx]*w;
            }
        }
    }
    ushort_t* dst = ht + ((b*24 + oy)*24)*256 + oc;
    #pragma unroll
    for (int ox=0; ox<24; ox++){
        float v = acc[ox];
        v = v > 0.f ? v : 0.01f*v;                        // leaky_relu
        dst[ox*256] = f2bf(v);
    }
}

// ---------------- conv2 as bf16 MFMA GEMM (im2col), K-split 4 ----------------
// A[m][k] = ht[b][2oy+ky][2ox+kx][ic], m=b*64+oy*8+ox, k=(ky*9+kx)*256+ic
// B[n][k] = w2t[oc][p][ic].  C -> p2p[ks][m][n] f32
__global__ __launch_bounds__(256) void k_conv2gemm(const ushort_t* __restrict__ ht,
    const ushort_t* __restrict__ w2t, float* __restrict__ p2p)
{
    __shared__ ushort_t At[128*64];
    __shared__ ushort_t Bt[64*64];
    const int tid = threadIdx.x;
    const int bid = blockIdx.x;
    const int mt = bid & 63, rest = bid >> 6;   // same-mt blocks share XCD (bid%8==mt%8)
    const int nt = rest & 3, ks = rest >> 2;
    const int m0 = mt*128, n0 = nt*64;
    const int lane = tid & 63, wave = tid >> 6;
    const int wm = (wave>>1)*64, wn = (wave&1)*32;
    const int l16 = lane & 15, lq = lane >> 4;

    f32x4 acc[4][2];
    #pragma unroll
    for (int i=0;i<4;i++)
        #pragma unroll
        for (int j=0;j<2;j++) acc[i][j] = 0;

    const ushort_t* abase[4];
    int aco[4];
    #pragma unroll
    for (int t=0;t<4;t++){
        int cid = tid + t*256;
        int row = cid>>3; aco[t] = cid&7;
        int m = m0 + row; int b = m>>6; int hw = m&63;
        int oy2 = hw>>3, ox2 = hw&7;
        abase[t] = ht + (((b*24 + 2*oy2)*24) + 2*ox2)*256;
    }
    int brow[2], bco[2];
    #pragma unroll
    for (int t=0;t<2;t++){
        int cid = tid + t*256;
        brow[t] = cid>>3; bco[t] = cid&7;
    }

    const int k_begin = ks*5184, k_end = k_begin + 5184;
    for (int k0 = k_begin; k0 < k_end; k0 += 64){
        const int p   = k0 >> 8;
        const int ky  = p/9, kx = p - ky*9;
        const int ic0 = k0 & 255;
        #pragma unroll
        for (int t=0;t<4;t++){
            bf16x8 v = *(const bf16x8*)(abase[t] + (ky*24 + kx)*256 + ic0 + aco[t]*8);
            *(bf16x8*)&At[(tid + t*256)*8] = v;
        }
        #pragma unroll
        for (int t=0;t<2;t++){
            bf16x8 v = *(const bf16x8*)(w2t + (n0+brow[t])*20736 + p*256 + ic0 + bco[t]*8);
            *(bf16x8*)&Bt[(tid + t*256)*8] = v;
        }
        __syncthreads();
        #pragma unroll
        for (int kk=0; kk<2; kk++){
            bf16x8 a[4], bf[2];
            const int kb = kk*32 + lq*8;
            #pragma unroll
            for (int f=0; f<4; f++) a[f]  = *(const bf16x8*)&At[(wm + f*16 + l16)*64 + kb];
            #pragma unroll
            for (int f=0; f<2; f++) bf[f] = *(const bf16x8*)&Bt[(wn + f*16 + l16)*64 + kb];
            #pragma unroll
            for (int i=0;i<4;i++)
                #pragma unroll
                for (int j=0;j<2;j++)
                    acc[i][j] = __builtin_amdgcn_mfma_f32_16x16x32_bf16(a[i], bf[j], acc[i][j], 0,0,0);
        }
        __syncthreads();
    }
    float* dst = p2p + (size_t)ks*2097152;
    #pragma unroll
    for (int i=0;i<4;i++)
        #pragma unroll
        for (int j=0;j<2;j++)
            #pragma unroll
            for (int r=0;r<4;r++){
                int m = m0 + wm + i*16 + lq*4 + r;          // C/D: row=(l>>4)*4+reg
                int n = n0 + wn + j*16 + l16;               //      col=l&15
                dst[m*256 + n] = acc[i][j][r];
            }
}

// ---------------- p (+bias) -> u (squashed), NEW layout u_r[n][b][8] ----------------
__global__ __launch_bounds__(256) void k_squash_u(const float* __restrict__ p2p,
    const float* __restrict__ prim_b, float* __restrict__ u)
{
    const int idx = blockIdx.x*256 + threadIdx.x;  // 0..262143 = b*2048+n
    const int b = idx >> 11, n = idx & 2047;
    const int hw = n >> 5, cap = n & 31;
    const int base = (b*64 + hw)*256 + cap*8;
    float v[8];
    #pragma unroll
    for (int j=0;j<8;j++) v[j] = prim_b[cap*8+j];
    #pragma unroll
    for (int ksp=0; ksp<4; ksp++){
        const float* sp = p2p + (size_t)ksp*2097152 + base;
        #pragma unroll
        for (int j=0;j<8;j++) v[j] += sp[j];
    }
    float s = 0.f;
    #pragma unroll
    for (int j=0;j<8;j++) s += v[j]*v[j];
    const float sc = sqrtf(s)/(1.0f + s);
    float* dst = u + ((size_t)n*128 + b)*8;
    #pragma unroll
    for (int j=0;j<8;j++) dst[j] = v[j]*sc;
}

// ---------------- routing pass (no logits storage: logits = uhat . S) ----------------
// thread = b (128/block), block = 4 nodes. W loads are block-uniform -> scalar loads.
// mode 0: probs uniform 0.1. mode 1: l = uhat.S, softmax over c, probs.
// Writes partials[block][b][c*16+d] = sum over this block's 4 nodes of p*uhat.
__global__ __launch_bounds__(128) void k_route2(const float* __restrict__ u_r,
    const float* __restrict__ dw, const float* __restrict__ S,
    float* __restrict__ partials, const int mode)
{
    __shared__ float lp[10*4*128];          // per-thread-private slots (dynamic c index)
    const int tid = threadIdx.x;            // = b
    const int n0 = blockIdx.x * 4;
    float uu[4][8];
    #pragma unroll
    for (int nl=0; nl<4; nl++){
        const float* up = u_r + ((size_t)(n0+nl)*128 + tid)*8;
        #pragma unroll
        for (int i=0;i<8;i++) uu[nl][i] = up[i];
    }
    if (mode){
        // phase A: l[c][nl] = sum_{i,d} u_i * W[c,n,i,d] * S[b,c,d]
        for (int c=0; c<10; c++){
            float Sc[16];
            const float* sp = S + tid*160 + c*16;
            #pragma unroll
            for (int d=0; d<16; d++) Sc[d] = sp[d];
            #pragma unroll
            for (int nl=0; nl<4; nl++){
                const float* wp = dw + ((size_t)(c*2048 + n0 + nl)*8)*16;
                float acc = 0.f;
                #pragma unroll
                for (int i=0;i<8;i++){
                    float t = 0.f;
                    #pragma unroll
                    for (int d=0; d<16; d++) t = fmaf(wp[i*16+d], Sc[d], t);
                    acc = fmaf(uu[nl][i], t, acc);
                }
                lp[(c*4+nl)*128 + tid] = acc;
            }
        }
        // softmax over c, in-register per node; p back into same LDS slots
        #pragma unroll
        for (int nl=0; nl<4; nl++){
            float l[10];
            #pragma unroll
            for (int c=0;c<10;c++) l[c] = lp[(c*4+nl)*128 + tid];
            float mx = l[0];
            #pragma unroll
            for (int c=1;c<10;c++) mx = fmaxf(mx, l[c]);
            float e[10], ssum = 0.f;
            #pragma unroll
            for (int c=0;c<10;c++){ e[c] = __expf(l[c]-mx); ssum += e[c]; }
            const float inv = 1.f/ssum;
            #pragma unroll
            for (int c=0;c<10;c++) lp[(c*4+nl)*128 + tid] = e[c]*inv;
        }
    }
    // phase B: partial out accumulation, 16 live acc regs per c
    float* dst = partials + ((size_t)blockIdx.x*128 + tid)*160;
    for (int c=0; c<10; c++){
        float oc[16];
        #pragma unroll
        for (int d=0;d<16;d++) oc[d]=0.f;
        #pragma unroll
        for (int nl=0; nl<4; nl++){
            const float pv = mode ? lp[(c*4+nl)*128 + tid] : 0.1f;
            const float* wp = dw + ((size_t)(c*2048 + n0 + nl)*8)*16;
            float ad[16];
            #pragma unroll
            for (int d=0;d<16;d++) ad[d]=0.f;
            #pragma unroll
            for (int i=0;i<8;i++)
                #pragma unroll
                for (int d=0;d<16;d++) ad[d] = fmaf(wp[i*16+d], uu[nl][i], ad[d]);
            #pragma unroll
            for (int d=0;d<16;d++) oc[d] = fmaf(pv, ad[d], oc[d]);
        }
        #pragma unroll
        for (int d=0;d<16;d++) dst[c*16+d] = oc[d];
    }
}

// out[b][c][d] = squash_d( sum_slots partials );  mode 0: S=val, 1: S+=val, 2: out=val
__global__ __launch_bounds__(256) void k_reduce2(const float* __restrict__ partials,
    float* __restrict__ S, float* __restrict__ outp, const int mode)
{
    const int c = blockIdx.x, b = blockIdx.y;
    const int t = threadIdx.x, d = t & 15, g = t >> 4;
    float s = 0.f;
    for (int sl = g; sl < 512; sl += 16)
        s += partials[((size_t)sl*128 + b)*160 + c*16 + d];
    __shared__ float red[256];
    red[t] = s;
    __syncthreads();
    if (g == 0){
        float v = red[d];
        #pragma unroll
        for (int k=1;k<16;k++) v += red[d + k*16];
        float ss = v*v;
        ss += __shfl_xor(ss, 1, 16);
        ss += __shfl_xor(ss, 2, 16);
        ss += __shfl_xor(ss, 4, 16);
        ss += __shfl_xor(ss, 8, 16);
        const float val = v * sqrtf(ss)/(1.f+ss);
        if (mode == 0)      S[b*160 + c*16 + d] = val;
        else if (mode == 1) S[b*160 + c*16 + d] += val;
        else                outp[(b*10 + c)*16 + d] = val;
    }
}

extern "C" void kernel_launch(void* const* d_in, const int* in_sizes, int n_in,
                              void* d_out, int out_size, void* d_ws, size_t ws_size,
                              hipStream_t stream)
{
    const float* x      = (const float*)d_in[0];
    const float* conv_w = (const float*)d_in[1];
    const float* conv_b = (const float*)d_in[2];
    const float* prim_w = (const float*)d_in[3];
    const float* prim_b = (const float*)d_in[4];
    const float* dig_w  = (const float*)d_in[5];
    float* out = (float*)d_out;
    char* ws = (char*)d_ws;

    // layout (bytes). partials/S overlay dead ht/w2t/cwt regions at routing time.
    ushort_t* ht       = (ushort_t*)(ws + 0);           // 37,748,736
    float*    partials = (float*)   (ws + 0);           // 41,943,040 (overlay)
    float*    S        = (float*)   (ws + 41943040);    //     81,920 (overlay)
    ushort_t* w2t      = (ushort_t*)(ws + 37748736);    // 10,616,832
    float*    cwt      = (float*)   (ws + 48365568);    //    248,832
    float*    p2p      = (float*)   (ws + 48614400);    // 33,554,432
    float*    u        = (float*)   (ws + 82168832);    //  8,388,608  -> 90,557,440 total

    k_w2t<<<1024, 256, 0, stream>>>(prim_w, w2t);
    k_cwt<<<243, 256, 0, stream>>>(conv_w, cwt);
    k_conv1<<<dim3(24,128), 256, 0, stream>>>(x, cwt, conv_b, ht);
    k_conv2gemm<<<1024, 256, 0, stream>>>(ht, w2t, p2p);
    k_squash_u<<<1024, 256, 0, stream>>>(p2p, prim_b, u);

    // routing: pass k uses S = sum of squashed outs so far (logits = uhat.S)
    k_route2<<<512, 128, 0, stream>>>(u, dig_w, S, partials, 0);
    k_reduce2<<<dim3(10,128), 256, 0, stream>>>(partials, S, out, 0);
    k_route2<<<512, 128, 0, stream>>>(u, dig_w, S, partials, 1);
    k_reduce2<<<dim3(10,128), 256, 0, stream>>>(partials, S, out, 1);
    k_route2<<<512, 128, 0, stream>>>(u, dig_w, S, partials, 1);
    k_reduce2<<<dim3(10,128), 256, 0, stream>>>(partials, S, out, 1);
    k_route2<<<512, 128, 0, stream>>>(u, dig_w, S, partials, 1);
    k_reduce2<<<dim3(10,128), 256, 0, stream>>>(partials, S, out, 2);
}

// Round 3
// 672.779 us; speedup vs baseline: 1.7678x; 1.1052x over previous
//
#include <hip/hip_runtime.h>
#include <hip/hip_bf16.h>

typedef __attribute__((ext_vector_type(8))) short bf16x8;
typedef __attribute__((ext_vector_type(4))) float f32x4;
typedef unsigned short ushort_t;

__device__ inline ushort_t f2bf(float f){
    union { float f; unsigned int u; } v; v.f = f;
    unsigned int r = v.u + 0x7fffu + ((v.u >> 16) & 1u);   // RNE
    return (ushort_t)(r >> 16);
}

// ---------------- weight transforms ----------------
// prim_w [256 oc][256 ic][81 p] f32  ->  w2t [oc][p][ic] bf16
__global__ __launch_bounds__(256) void k_w2t(const float* __restrict__ pw, ushort_t* __restrict__ w2t)
{
    __shared__ float tile[5184];             // [64 ic][81 p]
    const int oc  = blockIdx.x >> 2;
    const int ic0 = (blockIdx.x & 3) * 64;
    const float* src = pw + (oc*256 + ic0)*81;
    for (int j = threadIdx.x; j < 5184; j += 256) tile[j] = src[j];
    __syncthreads();
    for (int j = threadIdx.x; j < 5184; j += 256){
        int p = j >> 6, ic = j & 63;
        w2t[(oc*81 + p)*256 + ic0 + ic] = f2bf(tile[ic*81 + p]);
    }
}

// conv_w [256 oc][243 k] f32 -> cwt [243 k][256 oc] f32
__global__ void k_cwt(const float* __restrict__ cw, float* __restrict__ cwt){
    int k = blockIdx.x;           // 0..242
    int oc = threadIdx.x;         // 0..255
    cwt[k*256 + oc] = cw[oc*243 + k];
}

// ---------------- conv1 (fp32 direct) -> h_t[b][24][24][256] bf16 ----------------
__global__ __launch_bounds__(256) void k_conv1(const float* __restrict__ x,
    const float* __restrict__ cwt, const float* __restrict__ conv_b,
    ushort_t* __restrict__ ht)
{
    const int oy = blockIdx.x;    // 0..23
    const int b  = blockIdx.y;    // 0..127
    const int oc = threadIdx.x;   // 0..255
    float acc[24];
    const float bias = conv_b[oc];
    #pragma unroll
    for (int i=0;i<24;i++) acc[i] = bias;
    for (int ic=0; ic<3; ic++){
        for (int ky=0; ky<9; ky++){
            const float* xr = x + ((b*3 + ic)*32 + (oy+ky))*32;
            float xv[32];
            #pragma unroll
            for (int j=0;j<32;j++) xv[j] = xr[j];        // wave-uniform loads
            const float* wrow = cwt + (ic*81 + ky*9)*256 + oc;
            #pragma unroll
            for (int kx=0; kx<9; kx++){
                float w = wrow[kx*256];
                #pragma unroll
                for (int ox=0; ox<24; ox++) acc[ox] += xv[ox+kx]*w;
            }
        }
    }
    ushort_t* dst = ht + ((b*24 + oy)*24)*256 + oc;
    #pragma unroll
    for (int ox=0; ox<24; ox++){
        float v = acc[ox];
        v = v > 0.f ? v : 0.01f*v;                        // leaky_relu
        dst[ox*256] = f2bf(v);
    }
}

// ---------------- conv2 as bf16 MFMA GEMM (im2col), K-split 4, T2 swizzle -------
// A[m][k] = ht[b][2oy+ky][2ox+kx][ic], m=b*64+oy*8+ox, k=(ky*9+kx)*256+ic
// B[n][k] = w2t[oc][p][ic].  C -> p2p[ks][m][n] f32
// LDS tiles stored as 16B slots: slot(row,co) = row*8 + (co ^ (row&7))
__global__ __launch_bounds__(256) void k_conv2gemm(const ushort_t* __restrict__ ht,
    const ushort_t* __restrict__ w2t, float* __restrict__ p2p)
{
    __shared__ ushort_t At[128*64];
    __shared__ ushort_t Bt[64*64];
    const int tid = threadIdx.x;
    const int bid = blockIdx.x;
    const int mt = bid & 63, rest = bid >> 6;   // same-mt blocks share XCD (bid%8==mt%8)
    const int nt = rest & 3, ks = rest >> 2;
    const int m0 = mt*128, n0 = nt*64;
    const int lane = tid & 63, wave = tid >> 6;
    const int wm = (wave>>1)*64, wn = (wave&1)*32;
    const int l16 = lane & 15, lq = lane >> 4;
    const int rx = l16 & 7;                      // row&7 for all fragment rows

    f32x4 acc[4][2];
    #pragma unroll
    for (int i=0;i<4;i++)
        #pragma unroll
        for (int j=0;j<2;j++) acc[i][j] = 0;

    const ushort_t* abase[4];
    int aco[4], aswz[4];
    #pragma unroll
    for (int t=0;t<4;t++){
        int cid = tid + t*256;
        int row = cid>>3; aco[t] = cid&7;
        aswz[t] = (row*8 + (aco[t] ^ (row&7)))*8;
        int m = m0 + row; int b = m>>6; int hw = m&63;
        int oy2 = hw>>3, ox2 = hw&7;
        abase[t] = ht + (((b*24 + 2*oy2)*24) + 2*ox2)*256;
    }
    int brow[2], bco[2], bswz[2];
    #pragma unroll
    for (int t=0;t<2;t++){
        int cid = tid + t*256;
        brow[t] = cid>>3; bco[t] = cid&7;
        bswz[t] = (brow[t]*8 + (bco[t] ^ (brow[t]&7)))*8;
    }

    const int k_begin = ks*5184, k_end = k_begin + 5184;
    for (int k0 = k_begin; k0 < k_end; k0 += 64){
        const int p   = k0 >> 8;
        const int ky  = p/9, kx = p - ky*9;
        const int ic0 = k0 & 255;
        #pragma unroll
        for (int t=0;t<4;t++){
            bf16x8 v = *(const bf16x8*)(abase[t] + (ky*24 + kx)*256 + ic0 + aco[t]*8);
            *(bf16x8*)&At[aswz[t]] = v;
        }
        #pragma unroll
        for (int t=0;t<2;t++){
            bf16x8 v = *(const bf16x8*)(w2t + (n0+brow[t])*20736 + p*256 + ic0 + bco[t]*8);
            *(bf16x8*)&Bt[bswz[t]] = v;
        }
        __syncthreads();
        #pragma unroll
        for (int kk=0; kk<2; kk++){
            bf16x8 a[4], bf[2];
            const int co = kk*4 + lq;
            const int cs = (co ^ rx)*8;
            #pragma unroll
            for (int f=0; f<4; f++) a[f]  = *(const bf16x8*)&At[(wm + f*16 + l16)*64 + cs];
            #pragma unroll
            for (int f=0; f<2; f++) bf[f] = *(const bf16x8*)&Bt[(wn + f*16 + l16)*64 + cs];
            #pragma unroll
            for (int i=0;i<4;i++)
                #pragma unroll
                for (int j=0;j<2;j++)
                    acc[i][j] = __builtin_amdgcn_mfma_f32_16x16x32_bf16(a[i], bf[j], acc[i][j], 0,0,0);
        }
        __syncthreads();
    }
    float* dst = p2p + (size_t)ks*2097152;
    #pragma unroll
    for (int i=0;i<4;i++)
        #pragma unroll
        for (int j=0;j<2;j++)
            #pragma unroll
            for (int r=0;r<4;r++){
                int m = m0 + wm + i*16 + lq*4 + r;          // C/D: row=(l>>4)*4+reg
                int n = n0 + wn + j*16 + l16;               //      col=l&15
                dst[m*256 + n] = acc[i][j][r];
            }
}

// ---------------- p (+bias) -> u (squashed), layout u_r[n][b][8] ----------------
__global__ __launch_bounds__(256) void k_squash_u(const float* __restrict__ p2p,
    const float* __restrict__ prim_b, float* __restrict__ u)
{
    const int idx = blockIdx.x*256 + threadIdx.x;  // 0..262143 = b*2048+n
    const int b = idx >> 11, n = idx & 2047;
    const int hw = n >> 5, cap = n & 31;
    const int base = (b*64 + hw)*256 + cap*8;
    float v[8];
    #pragma unroll
    for (int j=0;j<8;j++) v[j] = prim_b[cap*8+j];
    #pragma unroll
    for (int ksp=0; ksp<4; ksp++){
        const float* sp = p2p + (size_t)ksp*2097152 + base;
        #pragma unroll
        for (int j=0;j<8;j++) v[j] += sp[j];
    }
    float s = 0.f;
    #pragma unroll
    for (int j=0;j<8;j++) s += v[j]*v[j];
    const float sc = sqrtf(s)/(1.0f + s);
    float* dst = u + ((size_t)n*128 + b)*8;
    #pragma unroll
    for (int j=0;j<8;j++) dst[j] = v[j]*sc;
}

// ---------------- routing pass: 512 blocks x 512 threads, 1 node/thread --------
// thread = (b = tid&127, h = tid>>7); node = bid*4 + h. logits = uhat . S (no storage).
// All softmax state in registers. Block-reduces its 4 nodes' p*uhat via LDS, writes
// partials[slot=bid][b][c*16+d] with 16B/lane dwordx4 stores.
__global__ __launch_bounds__(512) void k_route3(const float* __restrict__ u_r,
    const float* __restrict__ dw, const float* __restrict__ S,
    float* __restrict__ partials, const int mode)
{
    __shared__ float ored[4][16][128];      // 32 KB
    const int tid = threadIdx.x;
    const int b = tid & 127, h = tid >> 7;
    const int n = blockIdx.x*4 + h;
    float uu[8];
    const float* up = u_r + ((size_t)n*128 + b)*8;
    #pragma unroll
    for (int i=0;i<8;i++) uu[i] = up[i];

    float p[10];
    if (mode){
        float l[10];
        #pragma unroll
        for (int c=0;c<10;c++){
            const float* wp = dw + ((size_t)(c*2048 + n)*8)*16;
            float ad[16];
            #pragma unroll
            for (int d=0;d<16;d++) ad[d] = 0.f;
            #pragma unroll
            for (int i=0;i<8;i++)
                #pragma unroll
                for (int d=0;d<16;d++) ad[d] = fmaf(wp[i*16+d], uu[i], ad[d]);
            const float* sp = S + b*160 + c*16;
            float acc = 0.f;
            #pragma unroll
            for (int d=0;d<16;d++) acc = fmaf(ad[d], sp[d], acc);
            l[c] = acc;
        }
        float mx = l[0];
        #pragma unroll
        for (int c=1;c<10;c++) mx = fmaxf(mx, l[c]);
        float ssum = 0.f;
        #pragma unroll
        for (int c=0;c<10;c++){ p[c] = __expf(l[c]-mx); ssum += p[c]; }
        const float inv = 1.f/ssum;
        #pragma unroll
        for (int c=0;c<10;c++) p[c] *= inv;
    } else {
        #pragma unroll
        for (int c=0;c<10;c++) p[c] = 0.1f;
    }

    const int b2 = tid >> 2, dq = tid & 3;
    float* dstq = partials + ((size_t)blockIdx.x*128 + b2)*160 + dq*4;
    #pragma unroll
    for (int c=0;c<10;c++){
        const float* wp = dw + ((size_t)(c*2048 + n)*8)*16;
        float ad[16];
        #pragma unroll
        for (int d=0;d<16;d++) ad[d] = 0.f;
        #pragma unroll
        for (int i=0;i<8;i++)
            #pragma unroll
            for (int d=0;d<16;d++) ad[d] = fmaf(wp[i*16+d], uu[i], ad[d]);
        const float pc = p[c];
        #pragma unroll
        for (int d=0;d<16;d++) ored[h][d][b] = 0.f;   // (overwritten below; keeps pattern simple)
        #pragma unroll
        for (int d=0;d<16;d++) ored[h][d][b] = pc*ad[d];
        __syncthreads();
        f32x4 v;
        #pragma unroll
        for (int k=0;k<4;k++){
            int d = dq*4+k;
            v[k] = ored[0][d][b2] + ored[1][d][b2] + ored[2][d][b2] + ored[3][d][b2];
        }
        *(f32x4*)(dstq + c*16) = v;
        __syncthreads();
    }
}

// out[b][c][d] = squash_d( sum_slots partials );  mode 0: S=val, 1: S+=val, 2: out=val
__global__ __launch_bounds__(256) void k_reduce2(const float* __restrict__ partials,
    float* __restrict__ S, float* __restrict__ outp, const int mode)
{
    const int c = blockIdx.x, b = blockIdx.y;
    const int t = threadIdx.x, d = t & 15, g = t >> 4;
    float s = 0.f;
    for (int sl = g; sl < 512; sl += 16)
        s += partials[((size_t)sl*128 + b)*160 + c*16 + d];
    __shared__ float red[256];
    red[t] = s;
    __syncthreads();
    if (g == 0){
        float v = red[d];
        #pragma unroll
        for (int k=1;k<16;k++) v += red[d + k*16];
        float ss = v*v;
        ss += __shfl_xor(ss, 1, 16);
        ss += __shfl_xor(ss, 2, 16);
        ss += __shfl_xor(ss, 4, 16);
        ss += __shfl_xor(ss, 8, 16);
        const float val = v * sqrtf(ss)/(1.f+ss);
        if (mode == 0)      S[b*160 + c*16 + d] = val;
        else if (mode == 1) S[b*160 + c*16 + d] += val;
        else                outp[(b*10 + c)*16 + d] = val;
    }
}

extern "C" void kernel_launch(void* const* d_in, const int* in_sizes, int n_in,
                              void* d_out, int out_size, void* d_ws, size_t ws_size,
                              hipStream_t stream)
{
    const float* x      = (const float*)d_in[0];
    const float* conv_w = (const float*)d_in[1];
    const float* conv_b = (const float*)d_in[2];
    const float* prim_w = (const float*)d_in[3];
    const float* prim_b = (const float*)d_in[4];
    const float* dig_w  = (const float*)d_in[5];
    float* out = (float*)d_out;
    char* ws = (char*)d_ws;

    // layout (bytes). partials/S overlay dead ht/w2t/cwt regions at routing time.
    ushort_t* ht       = (ushort_t*)(ws + 0);           // 37,748,736
    float*    partials = (float*)   (ws + 0);           // 41,943,040 (overlay)
    float*    S        = (float*)   (ws + 41943040);    //     81,920 (overlay)
    ushort_t* w2t      = (ushort_t*)(ws + 37748736);    // 10,616,832
    float*    cwt      = (float*)   (ws + 48365568);    //    248,832
    float*    p2p      = (float*)   (ws + 48614400);    // 33,554,432
    float*    u        = (float*)   (ws + 82168832);    //  8,388,608  -> 90,557,440 total

    k_w2t<<<1024, 256, 0, stream>>>(prim_w, w2t);
    k_cwt<<<243, 256, 0, stream>>>(conv_w, cwt);
    k_conv1<<<dim3(24,128), 256, 0, stream>>>(x, cwt, conv_b, ht);
    k_conv2gemm<<<1024, 256, 0, stream>>>(ht, w2t, p2p);
    k_squash_u<<<1024, 256, 0, stream>>>(p2p, prim_b, u);

    // routing: pass k uses S = sum of squashed outs so far (logits = uhat.S)
    k_route3<<<512, 512, 0, stream>>>(u, dig_w, S, partials, 0);
    k_reduce2<<<dim3(10,128), 256, 0, stream>>>(partials, S, out, 0);
    k_route3<<<512, 512, 0, stream>>>(u, dig_w, S, partials, 1);
    k_reduce2<<<dim3(10,128), 256, 0, stream>>>(partials, S, out, 1);
    k_route3<<<512, 512, 0, stream>>>(u, dig_w, S, partials, 1);
    k_reduce2<<<dim3(10,128), 256, 0, stream>>>(partials, S, out, 1);
    k_route3<<<512, 512, 0, stream>>>(u, dig_w, S, partials, 1);
    k_reduce2<<<dim3(10,128), 256, 0, stream>>>(partials, S, out, 2);
}

// Round 4
// 488.899 us; speedup vs baseline: 2.4326x; 1.3761x over previous
//
#include <hip/hip_runtime.h>
#include <hip/hip_bf16.h>

typedef __attribute__((ext_vector_type(8))) short bf16x8;
typedef __attribute__((ext_vector_type(4))) float f32x4;
typedef unsigned short ushort_t;

__device__ inline ushort_t f2bf(float f){
    union { float f; unsigned int u; } v; v.f = f;
    unsigned int r = v.u + 0x7fffu + ((v.u >> 16) & 1u);   // RNE
    return (ushort_t)(r >> 16);
}

// ---------------- weight transforms ----------------
// prim_w [256 oc][256 ic][81 p] f32  ->  w2t [oc][p][ic] bf16
__global__ __launch_bounds__(256) void k_w2t(const float* __restrict__ pw, ushort_t* __restrict__ w2t)
{
    __shared__ float tile[5184];             // [64 ic][81 p]
    const int oc  = blockIdx.x >> 2;
    const int ic0 = (blockIdx.x & 3) * 64;
    const float* src = pw + (oc*256 + ic0)*81;
    for (int j = threadIdx.x; j < 5184; j += 256) tile[j] = src[j];
    __syncthreads();
    for (int j = threadIdx.x; j < 5184; j += 256){
        int p = j >> 6, ic = j & 63;
        w2t[(oc*81 + p)*256 + ic0 + ic] = f2bf(tile[ic*81 + p]);
    }
}

// conv_w [256 oc][243 k] f32 -> cwt [243 k][256 oc] f32
__global__ void k_cwt(const float* __restrict__ cw, float* __restrict__ cwt){
    int k = blockIdx.x;           // 0..242
    int oc = threadIdx.x;         // 0..255
    cwt[k*256 + oc] = cw[oc*243 + k];
}

// ---------------- conv1 (fp32 direct) -> h_t[b][24][24][256] bf16 ----------------
__global__ __launch_bounds__(256) void k_conv1(const float* __restrict__ x,
    const float* __restrict__ cwt, const float* __restrict__ conv_b,
    ushort_t* __restrict__ ht)
{
    const int oy = blockIdx.x;    // 0..23
    const int b  = blockIdx.y;    // 0..127
    const int oc = threadIdx.x;   // 0..255
    float acc[24];
    const float bias = conv_b[oc];
    #pragma unroll
    for (int i=0;i<24;i++) acc[i] = bias;
    for (int ic=0; ic<3; ic++){
        for (int ky=0; ky<9; ky++){
            const float* xr = x + ((b*3 + ic)*32 + (oy+ky))*32;
            float xv[32];
            #pragma unroll
            for (int j=0;j<32;j++) xv[j] = xr[j];        // wave-uniform loads
            const float* wrow = cwt + (ic*81 + ky*9)*256 + oc;
            #pragma unroll
            for (int kx=0; kx<9; kx++){
                float w = wrow[kx*256];
                #pragma unroll
                for (int ox=0; ox<24; ox++) acc[ox] += xv[ox+kx]*w;
            }
        }
    }
    ushort_t* dst = ht + ((b*24 + oy)*24)*256 + oc;
    #pragma unroll
    for (int ox=0; ox<24; ox++){
        float v = acc[ox];
        v = v > 0.f ? v : 0.01f*v;                        // leaky_relu
        dst[ox*256] = f2bf(v);
    }
}

// ---------------- conv2 as bf16 MFMA GEMM (im2col), K-split 4, T2 swizzle -------
// A[m][k] = ht[b][2oy+ky][2ox+kx][ic], m=b*64+oy*8+ox, k=(ky*9+kx)*256+ic
// B[n][k] = w2t[oc][p][ic].  C -> p2p[ks][m][n] f32
// LDS tiles stored as 16B slots: slot(row,co) = row*8 + (co ^ (row&7))
__global__ __launch_bounds__(256) void k_conv2gemm(const ushort_t* __restrict__ ht,
    const ushort_t* __restrict__ w2t, float* __restrict__ p2p)
{
    __shared__ ushort_t At[128*64];
    __shared__ ushort_t Bt[64*64];
    const int tid = threadIdx.x;
    const int bid = blockIdx.x;
    const int mt = bid & 63, rest = bid >> 6;   // same-mt blocks share XCD (bid%8==mt%8)
    const int nt = rest & 3, ks = rest >> 2;
    const int m0 = mt*128, n0 = nt*64;
    const int lane = tid & 63, wave = tid >> 6;
    const int wm = (wave>>1)*64, wn = (wave&1)*32;
    const int l16 = lane & 15, lq = lane >> 4;
    const int rx = l16 & 7;                      // row&7 for all fragment rows

    f32x4 acc[4][2];
    #pragma unroll
    for (int i=0;i<4;i++)
        #pragma unroll
        for (int j=0;j<2;j++) acc[i][j] = 0;

    const ushort_t* abase[4];
    int aco[4], aswz[4];
    #pragma unroll
    for (int t=0;t<4;t++){
        int cid = tid + t*256;
        int row = cid>>3; aco[t] = cid&7;
        aswz[t] = (row*8 + (aco[t] ^ (row&7)))*8;
        int m = m0 + row; int b = m>>6; int hw = m&63;
        int oy2 = hw>>3, ox2 = hw&7;
        abase[t] = ht + (((b*24 + 2*oy2)*24) + 2*ox2)*256;
    }
    int brow[2], bco[2], bswz[2];
    #pragma unroll
    for (int t=0;t<2;t++){
        int cid = tid + t*256;
        brow[t] = cid>>3; bco[t] = cid&7;
        bswz[t] = (brow[t]*8 + (bco[t] ^ (brow[t]&7)))*8;
    }

    const int k_begin = ks*5184, k_end = k_begin + 5184;
    for (int k0 = k_begin; k0 < k_end; k0 += 64){
        const int p   = k0 >> 8;
        const int ky  = p/9, kx = p - ky*9;
        const int ic0 = k0 & 255;
        #pragma unroll
        for (int t=0;t<4;t++){
            bf16x8 v = *(const bf16x8*)(abase[t] + (ky*24 + kx)*256 + ic0 + aco[t]*8);
            *(bf16x8*)&At[aswz[t]] = v;
        }
        #pragma unroll
        for (int t=0;t<2;t++){
            bf16x8 v = *(const bf16x8*)(w2t + (n0+brow[t])*20736 + p*256 + ic0 + bco[t]*8);
            *(bf16x8*)&Bt[bswz[t]] = v;
        }
        __syncthreads();
        #pragma unroll
        for (int kk=0; kk<2; kk++){
            bf16x8 a[4], bf[2];
            const int co = kk*4 + lq;
            const int cs = (co ^ rx)*8;
            #pragma unroll
            for (int f=0; f<4; f++) a[f]  = *(const bf16x8*)&At[(wm + f*16 + l16)*64 + cs];
            #pragma unroll
            for (int f=0; f<2; f++) bf[f] = *(const bf16x8*)&Bt[(wn + f*16 + l16)*64 + cs];
            #pragma unroll
            for (int i=0;i<4;i++)
                #pragma unroll
                for (int j=0;j<2;j++)
                    acc[i][j] = __builtin_amdgcn_mfma_f32_16x16x32_bf16(a[i], bf[j], acc[i][j], 0,0,0);
        }
        __syncthreads();
    }
    float* dst = p2p + (size_t)ks*2097152;
    #pragma unroll
    for (int i=0;i<4;i++)
        #pragma unroll
        for (int j=0;j<2;j++)
            #pragma unroll
            for (int r=0;r<4;r++){
                int m = m0 + wm + i*16 + lq*4 + r;          // C/D: row=(l>>4)*4+reg
                int n = n0 + wn + j*16 + l16;               //      col=l&15
                dst[m*256 + n] = acc[i][j][r];
            }
}

// ---------------- p (+bias) -> u (squashed), layout u_r[n][b][8] ----------------
__global__ __launch_bounds__(256) void k_squash_u(const float* __restrict__ p2p,
    const float* __restrict__ prim_b, float* __restrict__ u)
{
    const int idx = blockIdx.x*256 + threadIdx.x;  // 0..262143 = b*2048+n
    const int b = idx >> 11, n = idx & 2047;
    const int hw = n >> 5, cap = n & 31;
    const int base = (b*64 + hw)*256 + cap*8;
    float v[8];
    #pragma unroll
    for (int j=0;j<8;j++) v[j] = prim_b[cap*8+j];
    #pragma unroll
    for (int ksp=0; ksp<4; ksp++){
        const float* sp = p2p + (size_t)ksp*2097152 + base;
        #pragma unroll
        for (int j=0;j<8;j++) v[j] += sp[j];
    }
    float s = 0.f;
    #pragma unroll
    for (int j=0;j<8;j++) s += v[j]*v[j];
    const float sc = sqrtf(s)/(1.0f + s);
    float* dst = u + ((size_t)n*128 + b)*8;
    #pragma unroll
    for (int j=0;j<8;j++) dst[j] = v[j]*sc;
}

// ---------------- routing pass: 512 blocks x 512 threads, wave-uniform node -----
// thread = (b = tid&127, h = readfirstlane(tid>>7)); node = bid*4 + h.
// n wave-uniform => all dig_w addresses scalar => s_load via constant cache.
// logits = uhat.S (no logits storage). h-reduction via ping-pong LDS, 1 barrier/c.
__global__ __launch_bounds__(512) void k_route4(const float* __restrict__ u_r,
    const float* __restrict__ dw, const float* __restrict__ S,
    float* __restrict__ partials, const int mode)
{
    __shared__ float ored[2][4][16][129];   // ping-pong, pad 129 vs bank conflicts
    const int tid = threadIdx.x;
    const int b = tid & 127;
    const int h = __builtin_amdgcn_readfirstlane(tid >> 7);   // wave-uniform
    const int n = blockIdx.x*4 + h;
    const float* wbase = dw + (size_t)n*128;                  // + c*262144
    float uu[8];
    const float* up = u_r + ((size_t)n*128 + b)*8;
    #pragma unroll
    for (int i=0;i<8;i++) uu[i] = up[i];

    float p[10];
    if (mode){
        float l[10];
        #pragma unroll
        for (int c=0;c<10;c++){
            const float* wp = wbase + (size_t)c*262144;       // scalar loads
            float ad[16];
            #pragma unroll
            for (int d=0;d<16;d++) ad[d] = 0.f;
            #pragma unroll
            for (int i=0;i<8;i++)
                #pragma unroll
                for (int d=0;d<16;d++) ad[d] = fmaf(wp[i*16+d], uu[i], ad[d]);
            const float* sp = S + b*160 + c*16;
            float acc = 0.f;
            #pragma unroll
            for (int d=0;d<16;d++) acc = fmaf(ad[d], sp[d], acc);
            l[c] = acc;
        }
        float mx = l[0];
        #pragma unroll
        for (int c=1;c<10;c++) mx = fmaxf(mx, l[c]);
        float ssum = 0.f;
        #pragma unroll
        for (int c=0;c<10;c++){ p[c] = __expf(l[c]-mx); ssum += p[c]; }
        const float inv = 1.f/ssum;
        #pragma unroll
        for (int c=0;c<10;c++) p[c] *= inv;
    } else {
        #pragma unroll
        for (int c=0;c<10;c++) p[c] = 0.1f;
    }

    const int b2 = tid >> 2, dq = tid & 3;
    float* dstq = partials + ((size_t)blockIdx.x*128 + b2)*160 + dq*4;
    #pragma unroll
    for (int c=0;c<10;c++){
        const float* wp = wbase + (size_t)c*262144;           // scalar loads
        float ad[16];
        #pragma unroll
        for (int d=0;d<16;d++) ad[d] = 0.f;
        #pragma unroll
        for (int i=0;i<8;i++)
            #pragma unroll
            for (int d=0;d<16;d++) ad[d] = fmaf(wp[i*16+d], uu[i], ad[d]);
        const float pc = p[c];
        #pragma unroll
        for (int d=0;d<16;d++) ored[c&1][h][d][b] = pc*ad[d];
        __syncthreads();
        // read c's buffer; next iteration writes the other buffer, so no 2nd barrier
        f32x4 v;
        #pragma unroll
        for (int k=0;k<4;k++){
            const int d = dq*4+k;
            v[k] = ored[c&1][0][d][b2] + ored[c&1][1][d][b2]
                 + ored[c&1][2][d][b2] + ored[c&1][3][d][b2];
        }
        *(f32x4*)(dstq + c*16) = v;
    }
}

// out[b][c][d] = squash_d( sum_slots partials );  mode 0: S=val, 1: S+=val, 2: out=val
__global__ __launch_bounds__(256) void k_reduce2(const float* __restrict__ partials,
    float* __restrict__ S, float* __restrict__ outp, const int mode)
{
    const int c = blockIdx.x, b = blockIdx.y;
    const int t = threadIdx.x, d = t & 15, g = t >> 4;
    float s = 0.f;
    for (int sl = g; sl < 512; sl += 16)
        s += partials[((size_t)sl*128 + b)*160 + c*16 + d];
    __shared__ float red[256];
    red[t] = s;
    __syncthreads();
    if (g == 0){
        float v = red[d];
        #pragma unroll
        for (int k=1;k<16;k++) v += red[d + k*16];
        float ss = v*v;
        ss += __shfl_xor(ss, 1, 16);
        ss += __shfl_xor(ss, 2, 16);
        ss += __shfl_xor(ss, 4, 16);
        ss += __shfl_xor(ss, 8, 16);
        const float val = v * sqrtf(ss)/(1.f+ss);
        if (mode == 0)      S[b*160 + c*16 + d] = val;
        else if (mode == 1) S[b*160 + c*16 + d] += val;
        else                outp[(b*10 + c)*16 + d] = val;
    }
}

extern "C" void kernel_launch(void* const* d_in, const int* in_sizes, int n_in,
                              void* d_out, int out_size, void* d_ws, size_t ws_size,
                              hipStream_t stream)
{
    const float* x      = (const float*)d_in[0];
    const float* conv_w = (const float*)d_in[1];
    const float* conv_b = (const float*)d_in[2];
    const float* prim_w = (const float*)d_in[3];
    const float* prim_b = (const float*)d_in[4];
    const float* dig_w  = (const float*)d_in[5];
    float* out = (float*)d_out;
    char* ws = (char*)d_ws;

    // layout (bytes). partials/S overlay dead ht/w2t/cwt regions at routing time.
    ushort_t* ht       = (ushort_t*)(ws + 0);           // 37,748,736
    float*    partials = (float*)   (ws + 0);           // 41,943,040 (overlay)
    float*    S        = (float*)   (ws + 41943040);    //     81,920 (overlay)
    ushort_t* w2t      = (ushort_t*)(ws + 37748736);    // 10,616,832
    float*    cwt      = (float*)   (ws + 48365568);    //    248,832
    float*    p2p      = (float*)   (ws + 48614400);    // 33,554,432
    float*    u        = (float*)   (ws + 82168832);    //  8,388,608  -> 90,557,440 total

    k_w2t<<<1024, 256, 0, stream>>>(prim_w, w2t);
    k_cwt<<<243, 256, 0, stream>>>(conv_w, cwt);
    k_conv1<<<dim3(24,128), 256, 0, stream>>>(x, cwt, conv_b, ht);
    k_conv2gemm<<<1024, 256, 0, stream>>>(ht, w2t, p2p);
    k_squash_u<<<1024, 256, 0, stream>>>(p2p, prim_b, u);

    // routing: pass k uses S = sum of squashed outs so far (logits = uhat.S)
    k_route4<<<512, 512, 0, stream>>>(u, dig_w, S, partials, 0);
    k_reduce2<<<dim3(10,128), 256, 0, stream>>>(partials, S, out, 0);
    k_route4<<<512, 512, 0, stream>>>(u, dig_w, S, partials, 1);
    k_reduce2<<<dim3(10,128), 256, 0, stream>>>(partials, S, out, 1);
    k_route4<<<512, 512, 0, stream>>>(u, dig_w, S, partials, 1);
    k_reduce2<<<dim3(10,128), 256, 0, stream>>>(partials, S, out, 1);
    k_route4<<<512, 512, 0, stream>>>(u, dig_w, S, partials, 1);
    k_reduce2<<<dim3(10,128), 256, 0, stream>>>(partials, S, out, 2);
}

// Round 5
// 436.580 us; speedup vs baseline: 2.7242x; 1.1198x over previous
//
#include <hip/hip_runtime.h>
#include <hip/hip_bf16.h>

typedef __attribute__((ext_vector_type(8))) short bf16x8;
typedef __attribute__((ext_vector_type(4))) float f32x4;
typedef unsigned short ushort_t;

__device__ inline ushort_t f2bf(float f){
    union { float f; unsigned int u; } v; v.f = f;
    unsigned int r = v.u + 0x7fffu + ((v.u >> 16) & 1u);   // RNE
    return (ushort_t)(r >> 16);
}

__device__ inline void gload_lds16(const void* g, void* l){
    __builtin_amdgcn_global_load_lds(
        (const __attribute__((address_space(1))) unsigned int*)g,
        (__attribute__((address_space(3))) unsigned int*)l, 16, 0, 0);
}

// ---------------- weight transforms ----------------
// prim_w [256 oc][256 ic][81 p] f32  ->  w2t [oc][p][ic] bf16
__global__ __launch_bounds__(256) void k_w2t(const float* __restrict__ pw, ushort_t* __restrict__ w2t)
{
    __shared__ float tile[5184];             // [64 ic][81 p]
    const int oc  = blockIdx.x >> 2;
    const int ic0 = (blockIdx.x & 3) * 64;
    const float* src = pw + (oc*256 + ic0)*81;
    for (int j = threadIdx.x; j < 5184; j += 256) tile[j] = src[j];
    __syncthreads();
    for (int j = threadIdx.x; j < 5184; j += 256){
        int p = j >> 6, ic = j & 63;
        w2t[(oc*81 + p)*256 + ic0 + ic] = f2bf(tile[ic*81 + p]);
    }
}

// conv_w [256 oc][243 k] f32 -> cwt [243 k][256 oc] f32
__global__ void k_cwt(const float* __restrict__ cw, float* __restrict__ cwt){
    int k = blockIdx.x;           // 0..242
    int oc = threadIdx.x;         // 0..255
    cwt[k*256 + oc] = cw[oc*243 + k];
}

// ---------------- conv1 (fp32 direct) -> h_t[b][24][24][256] bf16 ----------------
__global__ __launch_bounds__(256) void k_conv1(const float* __restrict__ x,
    const float* __restrict__ cwt, const float* __restrict__ conv_b,
    ushort_t* __restrict__ ht)
{
    const int oy = blockIdx.x;    // 0..23
    const int b  = blockIdx.y;    // 0..127
    const int oc = threadIdx.x;   // 0..255
    float acc[24];
    const float bias = conv_b[oc];
    #pragma unroll
    for (int i=0;i<24;i++) acc[i] = bias;
    for (int ic=0; ic<3; ic++){
        for (int ky=0; ky<9; ky++){
            const float* xr = x + ((b*3 + ic)*32 + (oy+ky))*32;
            float xv[32];
            #pragma unroll
            for (int j=0;j<32;j++) xv[j] = xr[j];        // wave-uniform loads
            const float* wrow = cwt + (ic*81 + ky*9)*256 + oc;
            #pragma unroll
            for (int kx=0; kx<9; kx++){
                float w = wrow[kx*256];
                #pragma unroll
                for (int ox=0; ox<24; ox++) acc[ox] += xv[ox+kx]*w;
            }
        }
    }
    ushort_t* dst = ht + ((b*24 + oy)*24)*256 + oc;
    #pragma unroll
    for (int ox=0; ox<24; ox++){
        float v = acc[ox];
        v = v > 0.f ? v : 0.01f*v;                        // leaky_relu
        dst[ox*256] = f2bf(v);
    }
}

// ---------------- conv2: m97-style MFMA GEMM, global_load_lds staging ----------
// BM=128, BN=128, BK=64, 4 waves, wave-tile 64x64 (4x4 frags). K-split 4.
// LDS 16B slots swizzled: phys_slot(row,col) = row*8 + (col ^ (row&7)).
// global_load_lds writes linearly -> source address carries the inverse swizzle.
__global__ __launch_bounds__(256) void k_conv2gemm(const ushort_t* __restrict__ ht,
    const ushort_t* __restrict__ w2t, float* __restrict__ p2p)
{
    __shared__ ushort_t At[128*64];   // 16 KB
    __shared__ ushort_t Bt[128*64];   // 16 KB
    const int tid = threadIdx.x;
    const int bid = blockIdx.x;              // 512 blocks
    const int comb = bid & 7;                // = XCD id (round-robin dispatch)
    const int nt = comb & 1, ks = comb >> 1; // per-XCD: one (nt,ks) B-panel, L2-hot
    const int mt = bid >> 3;
    const int m0 = mt*128, n0 = nt*128;
    const int lane = tid & 63, wave = tid >> 6;
    const int wm = (wave >> 1)*64, wn = (wave & 1)*64;
    const int l16 = lane & 15, lq = lane >> 4;
    const int rx = l16 & 7;

    // staging sources (per-lane, pre-swizzled): wave w stages LDS insts w*4+t
    const int srow0 = wave*32 + (lane >> 3);
    const int cop = lane & 7;
    const ushort_t* asrc[4];
    const ushort_t* bsrc[4];
    #pragma unroll
    for (int t = 0; t < 4; t++){
        const int row = srow0 + t*8;
        const int col = cop ^ (row & 7);
        const int m = m0 + row;
        const int bi = m >> 6, hw = m & 63;
        const int oy2 = hw >> 3, ox2 = hw & 7;
        asrc[t] = ht + (((bi*24 + 2*oy2)*24) + 2*ox2)*256 + col*8;
        bsrc[t] = w2t + (size_t)(n0 + row)*20736 + col*8;
    }

    f32x4 acc[4][4];
    #pragma unroll
    for (int i=0;i<4;i++)
        #pragma unroll
        for (int j=0;j<4;j++) acc[i][j] = 0;

    const int k_begin = ks*5184;
    for (int step = 0; step < 81; step++){
        const int k0 = k_begin + step*64;
        const int pq = k0 >> 8;
        const int ky = pq/9, kx = pq - ky*9;
        const int aoff = (ky*24 + kx)*256 + (k0 & 255);
        #pragma unroll
        for (int t=0;t<4;t++){
            gload_lds16(asrc[t] + aoff, &At[(wave*4+t)*512]);
            gload_lds16(bsrc[t] + k0,  &Bt[(wave*4+t)*512]);
        }
        __syncthreads();
        #pragma unroll
        for (int kk=0; kk<2; kk++){
            bf16x8 a[4], bb[4];
            const int cs = ((kk*4 + lq) ^ rx)*8;
            #pragma unroll
            for (int f=0; f<4; f++){
                a[f]  = *(const bf16x8*)&At[(wm + f*16 + l16)*64 + cs];
                bb[f] = *(const bf16x8*)&Bt[(wn + f*16 + l16)*64 + cs];
            }
            #pragma unroll
            for (int i=0;i<4;i++)
                #pragma unroll
                for (int j=0;j<4;j++)
                    acc[i][j] = __builtin_amdgcn_mfma_f32_16x16x32_bf16(a[i], bb[j], acc[i][j], 0,0,0);
        }
        __syncthreads();
    }
    float* dst = p2p + (size_t)ks*2097152;
    #pragma unroll
    for (int i=0;i<4;i++)
        #pragma unroll
        for (int j=0;j<4;j++)
            #pragma unroll
            for (int r=0;r<4;r++){
                const int m = m0 + wm + i*16 + lq*4 + r;    // C/D: row=(l>>4)*4+reg
                const int n = n0 + wn + j*16 + l16;         //      col=l&15
                dst[m*256 + n] = acc[i][j][r];
            }
}

// ---------------- p (+bias) -> u (squashed), layout u_r[n][b][8] ----------------
__global__ __launch_bounds__(256) void k_squash_u(const float* __restrict__ p2p,
    const float* __restrict__ prim_b, float* __restrict__ u)
{
    const int idx = blockIdx.x*256 + threadIdx.x;  // 0..262143 = b*2048+n
    const int b = idx >> 11, n = idx & 2047;
    const int hw = n >> 5, cap = n & 31;
    const int base = (b*64 + hw)*256 + cap*8;
    float v[8];
    #pragma unroll
    for (int j=0;j<8;j++) v[j] = prim_b[cap*8+j];
    #pragma unroll
    for (int ksp=0; ksp<4; ksp++){
        const float* sp = p2p + (size_t)ksp*2097152 + base;
        #pragma unroll
        for (int j=0;j<8;j++) v[j] += sp[j];
    }
    float s = 0.f;
    #pragma unroll
    for (int j=0;j<8;j++) s += v[j]*v[j];
    const float sc = sqrtf(s)/(1.0f + s);
    float* dst = u + ((size_t)n*128 + b)*8;
    #pragma unroll
    for (int j=0;j<8;j++) dst[j] = v[j]*sc;
}

// ---------------- routing pass: W in LDS (broadcast reads), no logits storage ---
// 512 blocks x 512 threads; block = 4 nodes; thread (b=tid&127, h=tid>>7).
// W coop-loaded to LDS once (20 KB); reads are same-address broadcasts (free).
// logits = uhat.S recomputed; softmax in registers.
__global__ __launch_bounds__(512) void k_route5(const float* __restrict__ u_r,
    const float* __restrict__ dw, const float* __restrict__ S,
    float* __restrict__ partials, const int mode)
{
    __shared__ float Wl[4*10*128];          // 20 KB  [h][c][i*16+d]
    __shared__ float ored[4][16][129];      // 33 KB
    const int tid = threadIdx.x;
    const int b = tid & 127;
    const int h = __builtin_amdgcn_readfirstlane(tid >> 7);   // wave-uniform
    const int n0 = blockIdx.x*4;
    // cooperative W load: 1280 f32x4
    for (int v = tid; v < 1280; v += 512){
        const int hp = v/320, rem = v - hp*320, cp = rem >> 5, r4 = rem & 31;
        *(f32x4*)&Wl[hp*1280 + cp*128 + r4*4] =
            *(const f32x4*)(dw + (size_t)cp*262144 + (n0+hp)*128 + r4*4);
    }
    float uu[8];
    const float* up = u_r + ((size_t)(n0+h)*128 + b)*8;
    #pragma unroll
    for (int i=0;i<8;i++) uu[i] = up[i];
    __syncthreads();
    const float* wpb = &Wl[h*1280];

    float p[10];
    if (mode){
        float l[10];
        #pragma unroll
        for (int c=0;c<10;c++){
            const float* wp = wpb + c*128;                 // LDS broadcast
            float ad[16];
            #pragma unroll
            for (int d=0;d<16;d++) ad[d] = 0.f;
            #pragma unroll
            for (int i=0;i<8;i++)
                #pragma unroll
                for (int d=0;d<16;d++) ad[d] = fmaf(wp[i*16+d], uu[i], ad[d]);
            const float* sp = S + b*160 + c*16;
            float acc = 0.f;
            #pragma unroll
            for (int d=0;d<16;d++) acc = fmaf(ad[d], sp[d], acc);
            l[c] = acc;
        }
        float mx = l[0];
        #pragma unroll
        for (int c=1;c<10;c++) mx = fmaxf(mx, l[c]);
        float ssum = 0.f;
        #pragma unroll
        for (int c=0;c<10;c++){ p[c] = __expf(l[c]-mx); ssum += p[c]; }
        const float inv = 1.f/ssum;
        #pragma unroll
        for (int c=0;c<10;c++) p[c] *= inv;
    } else {
        #pragma unroll
        for (int c=0;c<10;c++) p[c] = 0.1f;
    }

    const int b2 = tid >> 2, dq = tid & 3;
    float* dstq = partials + ((size_t)blockIdx.x*128 + b2)*160 + dq*4;
    for (int c=0;c<10;c++){
        const float* wp = wpb + c*128;                     // LDS broadcast
        float ad[16];
        #pragma unroll
        for (int d=0;d<16;d++) ad[d] = 0.f;
        #pragma unroll
        for (int i=0;i<8;i++)
            #pragma unroll
            for (int d=0;d<16;d++) ad[d] = fmaf(wp[i*16+d], uu[i], ad[d]);
        const float pc = p[c];
        #pragma unroll
        for (int d=0;d<16;d++) ored[h][d][b] = pc*ad[d];
        __syncthreads();
        f32x4 v;
        #pragma unroll
        for (int k=0;k<4;k++){
            const int d = dq*4+k;
            v[k] = ored[0][d][b2] + ored[1][d][b2] + ored[2][d][b2] + ored[3][d][b2];
        }
        *(f32x4*)(dstq + c*16) = v;
        __syncthreads();
    }
}

// out[b][c][d] = squash_d( sum_slots partials );  mode 0: S=val, 1: S+=val, 2: out=val
__global__ __launch_bounds__(256) void k_reduce2(const float* __restrict__ partials,
    float* __restrict__ S, float* __restrict__ outp, const int mode)
{
    const int c = blockIdx.x, b = blockIdx.y;
    const int t = threadIdx.x, d = t & 15, g = t >> 4;
    float s = 0.f;
    for (int sl = g; sl < 512; sl += 16)
        s += partials[((size_t)sl*128 + b)*160 + c*16 + d];
    __shared__ float red[256];
    red[t] = s;
    __syncthreads();
    if (g == 0){
        float v = red[d];
        #pragma unroll
        for (int k=1;k<16;k++) v += red[d + k*16];
        float ss = v*v;
        ss += __shfl_xor(ss, 1, 16);
        ss += __shfl_xor(ss, 2, 16);
        ss += __shfl_xor(ss, 4, 16);
        ss += __shfl_xor(ss, 8, 16);
        const float val = v * sqrtf(ss)/(1.f+ss);
        if (mode == 0)      S[b*160 + c*16 + d] = val;
        else if (mode == 1) S[b*160 + c*16 + d] += val;
        else                outp[(b*10 + c)*16 + d] = val;
    }
}

extern "C" void kernel_launch(void* const* d_in, const int* in_sizes, int n_in,
                              void* d_out, int out_size, void* d_ws, size_t ws_size,
                              hipStream_t stream)
{
    const float* x      = (const float*)d_in[0];
    const float* conv_w = (const float*)d_in[1];
    const float* conv_b = (const float*)d_in[2];
    const float* prim_w = (const float*)d_in[3];
    const float* prim_b = (const float*)d_in[4];
    const float* dig_w  = (const float*)d_in[5];
    float* out = (float*)d_out;
    char* ws = (char*)d_ws;

    // layout (bytes). partials/S overlay dead ht/w2t/cwt regions at routing time.
    ushort_t* ht       = (ushort_t*)(ws + 0);           // 37,748,736
    float*    partials = (float*)   (ws + 0);           // 41,943,040 (overlay)
    float*    S        = (float*)   (ws + 41943040);    //     81,920 (overlay)
    ushort_t* w2t      = (ushort_t*)(ws + 37748736);    // 10,616,832
    float*    cwt      = (float*)   (ws + 48365568);    //    248,832
    float*    p2p      = (float*)   (ws + 48614400);    // 33,554,432
    float*    u        = (float*)   (ws + 82168832);    //  8,388,608  -> 90,557,440 total

    k_w2t<<<1024, 256, 0, stream>>>(prim_w, w2t);
    k_cwt<<<243, 256, 0, stream>>>(conv_w, cwt);
    k_conv1<<<dim3(24,128), 256, 0, stream>>>(x, cwt, conv_b, ht);
    k_conv2gemm<<<512, 256, 0, stream>>>(ht, w2t, p2p);
    k_squash_u<<<1024, 256, 0, stream>>>(p2p, prim_b, u);

    // routing: pass k uses S = sum of squashed outs so far (logits = uhat.S)
    k_route5<<<512, 512, 0, stream>>>(u, dig_w, S, partials, 0);
    k_reduce2<<<dim3(10,128), 256, 0, stream>>>(partials, S, out, 0);
    k_route5<<<512, 512, 0, stream>>>(u, dig_w, S, partials, 1);
    k_reduce2<<<dim3(10,128), 256, 0, stream>>>(partials, S, out, 1);
    k_route5<<<512, 512, 0, stream>>>(u, dig_w, S, partials, 1);
    k_reduce2<<<dim3(10,128), 256, 0, stream>>>(partials, S, out, 1);
    k_route5<<<512, 512, 0, stream>>>(u, dig_w, S, partials, 1);
    k_reduce2<<<dim3(10,128), 256, 0, stream>>>(partials, S, out, 2);
}